// Round 1
// baseline (235.154 us; speedup 1.0000x reference)
//
#include <hip/hip_runtime.h>
#include <cstdint>
#include <cstddef>

typedef unsigned short ushort_t;
typedef __attribute__((ext_vector_type(4))) float f32x4;
typedef __attribute__((ext_vector_type(8))) short s16x8;

#define PI_4F 0.78539816339744830962f

// round-to-nearest-even fp32 -> bf16
__device__ inline ushort_t f2bf(float f) {
  unsigned int u = __float_as_uint(f);
  u = u + 0x7fffu + ((u >> 16) & 1u);
  return (ushort_t)(u >> 16);
}

// ---------------------------------------------------------------------------
// Kernel 0: rot matrices -> global fp32. 64 threads, one per (b, n) pair.
// ---------------------------------------------------------------------------
__global__ void rot_kernel(const float* __restrict__ thetas, const float* __restrict__ scales,
                           const float* __restrict__ lambdas, float* __restrict__ rot) {
  int tid = threadIdx.x;  // 0..63 == b*4 + n
  float t = thetas[tid], s = scales[tid], lam = lambdas[tid];
  float xv = cosf(t) * s, yv = sinf(t) * s;
  bool pos = (t >= 0.0f), big = (s >= 1.0f), m1 = (fabsf(t) <= PI_4F);
  float M[81];
#pragma unroll
  for (int i = 0; i < 81; ++i) M[i] = 0.0f;
  M[36 + 4] = 1.0f;
  if (pos) {
    float a = xv - yv, bb = xv * yv, c = xv + yv;
    if (m1 && big) {  // pb1
      M[0] = a; M[1] = 1 - a;
      M[9 + 1] = 1 - yv; M[9 + 2] = yv;
      M[18 + 2] = a; M[18 + 5] = 1 - a;
      M[27 + 0] = yv; M[27 + 3] = 1 - yv;
      M[45 + 5] = 1 - yv; M[45 + 8] = yv;
      M[54 + 3] = 1 - a; M[54 + 6] = a;
      M[63 + 6] = yv; M[63 + 7] = 1 - yv;
      M[72 + 7] = 1 - a; M[72 + 8] = a;
    } else if (m1) {  // ps1
      float d = a * c, e = a + c;
      M[0] = d; M[1] = a - d; M[3] = c - d; M[4] = 1 - e + d;
      M[9 + 1] = xv - bb; M[9 + 2] = bb; M[9 + 4] = 1 - c + bb; M[9 + 5] = yv - bb;
      M[18 + 1] = c - d; M[18 + 2] = d; M[18 + 4] = 1 - e + d; M[18 + 5] = a - d;
      M[27 + 0] = bb; M[27 + 1] = yv - bb; M[27 + 3] = xv - bb; M[27 + 4] = 1 - c + bb;
      M[45 + 4] = 1 - c + bb; M[45 + 5] = xv - bb; M[45 + 7] = yv - bb; M[45 + 8] = bb;
      M[54 + 3] = a - d; M[54 + 4] = 1 - e + d; M[54 + 6] = d; M[54 + 7] = c - d;
      M[63 + 3] = yv - bb; M[63 + 4] = 1 - c + bb; M[63 + 6] = bb; M[63 + 7] = xv - bb;
      M[72 + 4] = 1 - e + d; M[72 + 5] = c - d; M[72 + 7] = a - d; M[72 + 8] = d;
    } else {  // pb2 == ps2
      M[0] = a; M[1] = 1 - a;
      M[9 + 1] = xv - bb; M[9 + 2] = bb; M[9 + 4] = 1 - c + bb; M[9 + 5] = yv - bb;
      M[18 + 2] = a; M[18 + 5] = 1 - a;
      M[27 + 0] = bb; M[27 + 1] = yv - bb; M[27 + 3] = xv - bb; M[27 + 4] = 1 - c + bb;
      M[45 + 4] = 1 - c + bb; M[45 + 5] = xv - bb; M[45 + 7] = yv - bb; M[45 + 8] = bb;
      M[54 + 3] = 1 - a; M[54 + 6] = a;
      M[63 + 3] = yv - bb; M[63 + 4] = 1 - c + bb; M[63 + 6] = bb; M[63 + 7] = xv - bb;
      M[72 + 7] = 1 - a; M[72 + 8] = a;
    }
  } else {
    float yp = -yv;
    float ap = xv - yp, bp = xv * yp, cp = xv + yp;
    if (m1 && big) {  // nb1
      M[0] = cp; M[3] = 1 - cp;
      M[9 + 0] = yp; M[9 + 1] = 1 - yp;
      M[18 + 1] = 1 - cp; M[18 + 2] = cp;
      M[27 + 3] = 1 - yp; M[27 + 6] = yp;
      M[45 + 2] = yp; M[45 + 5] = 1 - yp;
      M[54 + 6] = cp; M[54 + 7] = 1 - cp;
      M[63 + 7] = 1 - yp; M[63 + 8] = yp;
      M[72 + 5] = 1 - cp; M[72 + 8] = cp;
    } else if (m1) {  // ns1
      float dp = ap * cp, ep = ap + cp;
      M[0] = dp; M[1] = cp - dp; M[3] = ap - dp; M[4] = 1 - ep + dp;
      M[9 + 0] = bp; M[9 + 1] = xv - bp; M[9 + 3] = yp - bp; M[9 + 4] = 1 - cp + bp;
      M[18 + 1] = ap - dp; M[18 + 2] = dp; M[18 + 4] = 1 - ep + dp; M[18 + 5] = cp - dp;
      M[27 + 1] = yp - bp; M[27 + 2] = bp; M[27 + 4] = 1 - cp + bp; M[27 + 5] = xv - bp;
      M[45 + 3] = xv - bp; M[45 + 4] = 1 - cp + bp; M[45 + 6] = bp; M[45 + 7] = yp - bp;
      M[54 + 3] = cp - dp; M[54 + 4] = 1 - ep + dp; M[54 + 6] = dp; M[54 + 7] = ap - dp;
      M[63 + 4] = 1 - cp + bp; M[63 + 5] = yp - bp; M[63 + 7] = xv - bp; M[63 + 8] = bp;
      M[72 + 4] = 1 - ep + dp; M[72 + 5] = ap - dp; M[72 + 7] = cp - dp; M[72 + 8] = dp;
    } else {  // nb2 == ns2
      M[0] = cp; M[3] = 1 - cp;
      M[9 + 0] = bp; M[9 + 1] = xv - bp; M[9 + 3] = yp - bp; M[9 + 4] = 1 - cp + bp;
      M[18 + 1] = 1 - cp; M[18 + 2] = cp;
      M[27 + 3] = xv - bp; M[27 + 4] = 1 - cp + bp; M[27 + 6] = bp; M[27 + 7] = yp - bp;
      M[45 + 1] = yp - bp; M[45 + 2] = bp; M[45 + 4] = 1 - cp + bp; M[45 + 5] = xv - bp;
      M[54 + 6] = cp; M[54 + 7] = 1 - cp;
      M[63 + 4] = 1 - cp + bp; M[63 + 5] = yp - bp; M[63 + 7] = xv - bp; M[63 + 8] = bp;
      M[72 + 5] = 1 - cp; M[72 + 8] = cp;
    }
  }
  float* r = rot + tid * 81;
#pragma unroll
  for (int i = 0; i < 81; ++i) r[i] = M[i] * lam;
}

// ---------------------------------------------------------------------------
// Kernel 1: Wt[b][i][o][c] (bf16) = sum_n sum_j rot[b,n,i,j] * weight[n,o,c,j]
// Grid: (256 o, 4 bgroup), 128 threads; each thread owns 2 adjacent c so the
// output store is a packed 4B dword (old version did 2B scalar stores).
// Weight reads are 18 contiguous floats/lane -> dwordx4s.
// ---------------------------------------------------------------------------
__global__ __launch_bounds__(128) void wt_kernel(const float* __restrict__ weight,
                                                 const float* __restrict__ rot,
                                                 ushort_t* __restrict__ wtout) {
  const int o = blockIdx.x, bg = blockIdx.y;
  const int cid = threadIdx.x;  // 0..127
  const int c = cid * 2;
  float wv0[4][9], wv1[4][9];
#pragma unroll
  for (int n = 0; n < 4; ++n) {
    const float* wp = weight + (((size_t)(n * 256 + o)) * 256 + c) * 9;
#pragma unroll
    for (int j = 0; j < 9; ++j) { wv0[n][j] = wp[j]; wv1[n][j] = wp[9 + j]; }
  }
#pragma unroll
  for (int bl = 0; bl < 4; ++bl) {
    const int b = bg * 4 + bl;
#pragma unroll
    for (int i = 0; i < 9; ++i) {
      float a0 = 0.0f, a1 = 0.0f;
#pragma unroll
      for (int n = 0; n < 4; ++n) {
        const float* r = rot + (b * 4 + n) * 81 + i * 9;
#pragma unroll
        for (int j = 0; j < 9; ++j) {
          a0 = fmaf(r[j], wv0[n][j], a0);
          a1 = fmaf(r[j], wv1[n][j], a1);
        }
      }
      unsigned int word = (unsigned int)f2bf(a0) | ((unsigned int)f2bf(a1) << 16);
      *(unsigned int*)&wtout[((size_t)((b * 9 + i) * 256 + o)) * 256 + c] = word;
    }
  }
}

// ---------------------------------------------------------------------------
// Kernel 2: x [b][c][h][w] fp32 -> xpad [b][h+1][w+1][c] bf16, with the pad
// border zeroing fused in (replaces the old border_zero launch).
// float4 global loads (16B/lane) instead of scalar dwords.
// ---------------------------------------------------------------------------
__global__ __launch_bounds__(256) void transpose_kernel(const float* __restrict__ x,
                                                        ushort_t* __restrict__ xpad) {
  __shared__ ushort_t tile[64][68];  // 68: keeps uint2 reads 8B-aligned, breaks pow2 stride
  const int b = blockIdx.z, ct = blockIdx.y, st = blockIdx.x;  // st = h row
  const int t = threadIdx.x;
  const int c0 = ct * 64;
  const float* xb = x + ((size_t)(b * 256 + c0)) * 4096 + st * 64;
#pragma unroll
  for (int k = 0; k < 4; ++k) {
    int idx = t + 256 * k;            // 0..1023 over (c_l 0..63) x (w4 0,4,..60)
    int c_l = idx >> 4, w4 = (idx & 15) * 4;
    float4 v = *(const float4*)&xb[(size_t)c_l * 4096 + w4];
    tile[w4 + 0][c_l] = f2bf(v.x);
    tile[w4 + 1][c_l] = f2bf(v.y);
    tile[w4 + 2][c_l] = f2bf(v.z);
    tile[w4 + 3][c_l] = f2bf(v.w);
  }
  __syncthreads();
  const int c4 = (t & 15) * 4, wl = t >> 4;
  const size_t rowbase = (size_t)(b * 4356 + (st + 1) * 66) * 256 + c0;
#pragma unroll
  for (int k = 0; k < 4; ++k) {
    int w = wl + 16 * k;
    uint2 v = *(const uint2*)&tile[w][c4];
    *(uint2*)&xpad[rowbase + (size_t)(w + 1) * 256 + c4] = v;
  }
  // fused border zeroing; union over all blocks == old border_zero coverage:
  //   every block: w=0 and w=65 at h=st+1 for its c-slice
  if (t < 32) {
    int w = (t & 16) ? 65 : 0;
    int cc = (t & 15) * 4;
    *(uint2*)&xpad[rowbase + (size_t)w * 256 + cc] = make_uint2(0u, 0u);
  }
  //   st==0 blocks: full h=0 row; st==63 blocks: full h=65 row (their c-slice)
  if (st == 0 || st == 63) {
    const int h = (st == 0) ? 0 : 65;
    const size_t hb = (size_t)(b * 4356 + h * 66) * 256 + c0;
    for (int idx = t; idx < 66 * 16; idx += 256) {
      int w = idx >> 4, cc = (idx & 15) * 4;
      *(uint2*)&xpad[hb + (size_t)w * 256 + cc] = make_uint2(0u, 0u);
    }
  }
}

// ---------------------------------------------------------------------------
// Kernel 3: implicit-GEMM conv, bf16 MFMA.
// Tile 256 o x 128 hw, BK=32, 72 K-steps, 512 threads (8 waves, 64x64/wave).
// 512 blocks = exactly 2/CU. LDS: SIX statically distinct buffers (3-stage
// pipeline, 72 KB). Raw s_barrier + s_waitcnt vmcnt(3): prefetch stays in
// flight across the barrier; never drains to 0 except the peeled tail.
// NEW this round: T5 s_setprio(1) around the MFMA cluster — the schedule has
// wave role-split (stage-issuing vs MFMA-entering), the regime where T5 pays.
// ---------------------------------------------------------------------------
__device__ inline void gload16(const ushort_t* g, ushort_t* l) {
  __builtin_amdgcn_global_load_lds(
      (const __attribute__((address_space(1))) unsigned int*)g,
      (__attribute__((address_space(3))) unsigned int*)l, 16, 0, 0);
}

#define WAITB(N)                                                      \
  asm volatile("s_waitcnt vmcnt(" #N ") lgkmcnt(0)\n\ts_barrier" ::: "memory")

__global__ __launch_bounds__(512, 4) void conv_kernel(
    const ushort_t* __restrict__ xpad, const ushort_t* __restrict__ wt,
    float* __restrict__ out) {
  // six statically distinct LDS objects
  __shared__ __align__(16) ushort_t As0[8192], As1[8192], As2[8192];  // 16 KB each
  __shared__ __align__(16) ushort_t Bs0[4096], Bs1[4096], Bs2[4096];  //  8 KB each

  const int id = blockIdx.x;
  const int xcd = id & 7;
  const int jj = id >> 3;               // 0..63 within XCD
  const int b = xcd * 2 + (jj >> 5);    // 2 batches per XCD
  const int ntile = jj & 31;

  const int t = threadIdx.x;
  const int wave = t >> 6, lane = t & 63;
  const int wm = wave & 3, wn = wave >> 2;
  const int lr = lane & 15, lq = lane >> 4;
  const int h0 = ntile * 2;

  const ushort_t* wt_b = wt + (size_t)b * 589824;     // 9*256*256
  const ushort_t* xp_b = xpad + (size_t)b * 1115136;  // 4356*256

  const int lrow = t >> 2;                           // 0..127
  const int cg8 = (((t & 3) ^ ((t >> 3) & 3)) * 8);  // swizzled global 16B chunk
  const int rsw = (lr >> 1) & 3;
  const int aoff = (wm * 64 + lr) * 32 + ((lq ^ rsw) * 8);
  const int boff = (wn * 64 + lr) * 32 + ((lq ^ rsw) * 8);
  const int nrow2 = 2 * (lrow >> 6);  // xpad row-adjust for B n>=64

  f32x4 acc[4][4];
#pragma unroll
  for (int i = 0; i < 4; ++i)
#pragma unroll
    for (int j2 = 0; j2 < 4; ++j2) acc[i][j2] = (f32x4)(0.0f);

  auto stage = [&](int ks, ushort_t* Ad, ushort_t* Bd) {
    const int tap = ks >> 3;
    const int c0k = (ks & 7) << 5;
    const int kh = tap / 3, kw = tap - kh * 3;
    // A: Wt[b][tap][o 0..255][c0k..+31]; rows lrow and lrow+128
    const ushort_t* ga = wt_b + ((size_t)(tap * 256 + lrow)) * 256 + c0k + cg8;
    gload16(ga, Ad + wave * 512);
    gload16(ga + 128 * 256, Ad + 4096 + wave * 512);
    // B: n = lrow (0..127) -> spatial (h0 + n/64 + kh, n%64 + kw)
    const int sp = (h0 + kh) * 66 + kw + lrow + nrow2;
    gload16(xp_b + (size_t)sp * 256 + c0k + cg8, Bd + wave * 512);
  };

  auto compute = [&](const ushort_t* Ab, const ushort_t* Bb) {
    s16x8 bfr[4];
#pragma unroll
    for (int ni = 0; ni < 4; ++ni)
      bfr[ni] = *(const s16x8*)(Bb + boff + ni * 512);
    __builtin_amdgcn_s_setprio(1);
#pragma unroll
    for (int mi = 0; mi < 4; ++mi) {
      s16x8 af = *(const s16x8*)(Ab + aoff + mi * 512);
#pragma unroll
      for (int ni = 0; ni < 4; ++ni)
        acc[mi][ni] = __builtin_amdgcn_mfma_f32_16x16x32_bf16(af, bfr[ni], acc[mi][ni], 0, 0, 0);
    }
    __builtin_amdgcn_s_setprio(0);
  };

  stage(0, As0, Bs0);
  stage(1, As1, Bs1);

  // 23 unrolled triples: compute ks = 0..68, stage through ks = 70.
#pragma unroll 1
  for (int kk = 0; kk < 23; ++kk) {
    const int ks = kk * 3;
    WAITB(3);                      // stage(ks) resident; stage(ks+1) in flight
    stage(ks + 2, As2, Bs2);
    compute(As0, Bs0);
    WAITB(3);
    stage(ks + 3, As0, Bs0);
    compute(As1, Bs1);
    WAITB(3);
    stage(ks + 4, As1, Bs1);
    compute(As2, Bs2);
  }
  // tail: outstanding = stage69 (As0), stage70 (As1)
  WAITB(3);                        // stage69 resident
  stage(71, As2, Bs2);
  compute(As0, Bs0);               // ks = 69
  WAITB(3);                        // stage70 resident (71's 3 in flight)
  compute(As1, Bs1);               // ks = 70
  WAITB(0);                        // full drain
  compute(As2, Bs2);               // ks = 71

  // Epilogue. C/D layout (m89): col(n) = lane&15, row(m) = (lane>>4)*4 + reg
  float* ob = out + ((size_t)(b * 256 + wm * 64)) * 4096 + ntile * 128 + wn * 64 + lr;
#pragma unroll
  for (int mi = 0; mi < 4; ++mi)
#pragma unroll
    for (int r = 0; r < 4; ++r) {
      float* orow = ob + (size_t)(mi * 16 + lq * 4 + r) * 4096;
#pragma unroll
      for (int ni = 0; ni < 4; ++ni) orow[ni * 16] = acc[mi][ni][r];
    }
}

// ---------------------------------------------------------------------------
extern "C" void kernel_launch(void* const* d_in, const int* in_sizes, int n_in,
                              void* d_out, int out_size, void* d_ws, size_t ws_size,
                              hipStream_t stream) {
  const float* x = (const float*)d_in[0];       // [16,256,64,64]
  const float* thetas = (const float*)d_in[1];  // [16,4]
  const float* scales = (const float*)d_in[2];  // [16,4]
  const float* lambdas = (const float*)d_in[3]; // [16,4]
  const float* weight = (const float*)d_in[4];  // [4,256,256,3,3]
  float* out = (float*)d_out;                   // [16,256,64,64]

  // workspace layout:
  //   rot  fp32 [64][81]            @ 0        (padded to 32 KB)
  //   Wt   bf16 [16][9][256][256]   @ 32768    (18874368 B)
  //   xpad bf16 [16][66][66][256]   @ 18907136 (35684352 B)
  float* rot_ws = (float*)d_ws;
  ushort_t* wt_ws = (ushort_t*)((char*)d_ws + 32768);
  ushort_t* xpad_ws = (ushort_t*)((char*)d_ws + 32768 + 18874368);

  rot_kernel<<<1, 64, 0, stream>>>(thetas, scales, lambdas, rot_ws);
  wt_kernel<<<dim3(256, 4), 128, 0, stream>>>(weight, rot_ws, wt_ws);
  transpose_kernel<<<dim3(64, 4, 16), 256, 0, stream>>>(x, xpad_ws);
  conv_kernel<<<512, 512, 0, stream>>>(xpad_ws, wt_ws, out);
}

// Round 2
// 215.761 us; speedup vs baseline: 1.0899x; 1.0899x over previous
//
#include <hip/hip_runtime.h>
#include <cstdint>
#include <cstddef>

typedef unsigned short ushort_t;
typedef __attribute__((ext_vector_type(4))) float f32x4;
typedef __attribute__((ext_vector_type(8))) short s16x8;

#define PI_4F 0.78539816339744830962f

// round-to-nearest-even fp32 -> bf16
__device__ inline ushort_t f2bf(float f) {
  unsigned int u = __float_as_uint(f);
  u = u + 0x7fffu + ((u >> 16) & 1u);
  return (ushort_t)(u >> 16);
}

// ---------------------------------------------------------------------------
// rot matrix for one (b, n): fills M[81] (unscaled).
// ---------------------------------------------------------------------------
__device__ void rot_compute(float t, float s, float* M) {
  float xv = cosf(t) * s, yv = sinf(t) * s;
  bool pos = (t >= 0.0f), big = (s >= 1.0f), m1 = (fabsf(t) <= PI_4F);
#pragma unroll
  for (int i = 0; i < 81; ++i) M[i] = 0.0f;
  M[36 + 4] = 1.0f;
  if (pos) {
    float a = xv - yv, bb = xv * yv, c = xv + yv;
    if (m1 && big) {  // pb1
      M[0] = a; M[1] = 1 - a;
      M[9 + 1] = 1 - yv; M[9 + 2] = yv;
      M[18 + 2] = a; M[18 + 5] = 1 - a;
      M[27 + 0] = yv; M[27 + 3] = 1 - yv;
      M[45 + 5] = 1 - yv; M[45 + 8] = yv;
      M[54 + 3] = 1 - a; M[54 + 6] = a;
      M[63 + 6] = yv; M[63 + 7] = 1 - yv;
      M[72 + 7] = 1 - a; M[72 + 8] = a;
    } else if (m1) {  // ps1
      float d = a * c, e = a + c;
      M[0] = d; M[1] = a - d; M[3] = c - d; M[4] = 1 - e + d;
      M[9 + 1] = xv - bb; M[9 + 2] = bb; M[9 + 4] = 1 - c + bb; M[9 + 5] = yv - bb;
      M[18 + 1] = c - d; M[18 + 2] = d; M[18 + 4] = 1 - e + d; M[18 + 5] = a - d;
      M[27 + 0] = bb; M[27 + 1] = yv - bb; M[27 + 3] = xv - bb; M[27 + 4] = 1 - c + bb;
      M[45 + 4] = 1 - c + bb; M[45 + 5] = xv - bb; M[45 + 7] = yv - bb; M[45 + 8] = bb;
      M[54 + 3] = a - d; M[54 + 4] = 1 - e + d; M[54 + 6] = d; M[54 + 7] = c - d;
      M[63 + 3] = yv - bb; M[63 + 4] = 1 - c + bb; M[63 + 6] = bb; M[63 + 7] = xv - bb;
      M[72 + 4] = 1 - e + d; M[72 + 5] = c - d; M[72 + 7] = a - d; M[72 + 8] = d;
    } else {  // pb2 == ps2
      M[0] = a; M[1] = 1 - a;
      M[9 + 1] = xv - bb; M[9 + 2] = bb; M[9 + 4] = 1 - c + bb; M[9 + 5] = yv - bb;
      M[18 + 2] = a; M[18 + 5] = 1 - a;
      M[27 + 0] = bb; M[27 + 1] = yv - bb; M[27 + 3] = xv - bb; M[27 + 4] = 1 - c + bb;
      M[45 + 4] = 1 - c + bb; M[45 + 5] = xv - bb; M[45 + 7] = yv - bb; M[45 + 8] = bb;
      M[54 + 3] = 1 - a; M[54 + 6] = a;
      M[63 + 3] = yv - bb; M[63 + 4] = 1 - c + bb; M[63 + 6] = bb; M[63 + 7] = xv - bb;
      M[72 + 7] = 1 - a; M[72 + 8] = a;
    }
  } else {
    float yp = -yv;
    float ap = xv - yp, bp = xv * yp, cp = xv + yp;
    if (m1 && big) {  // nb1
      M[0] = cp; M[3] = 1 - cp;
      M[9 + 0] = yp; M[9 + 1] = 1 - yp;
      M[18 + 1] = 1 - cp; M[18 + 2] = cp;
      M[27 + 3] = 1 - yp; M[27 + 6] = yp;
      M[45 + 2] = yp; M[45 + 5] = 1 - yp;
      M[54 + 6] = cp; M[54 + 7] = 1 - cp;
      M[63 + 7] = 1 - yp; M[63 + 8] = yp;
      M[72 + 5] = 1 - cp; M[72 + 8] = cp;
    } else if (m1) {  // ns1
      float dp = ap * cp, ep = ap + cp;
      M[0] = dp; M[1] = cp - dp; M[3] = ap - dp; M[4] = 1 - ep + dp;
      M[9 + 0] = bp; M[9 + 1] = xv - bp; M[9 + 3] = yp - bp; M[9 + 4] = 1 - cp + bp;
      M[18 + 1] = ap - dp; M[18 + 2] = dp; M[18 + 4] = 1 - ep + dp; M[18 + 5] = cp - dp;
      M[27 + 1] = yp - bp; M[27 + 2] = bp; M[27 + 4] = 1 - cp + bp; M[27 + 5] = xv - bp;
      M[45 + 3] = xv - bp; M[45 + 4] = 1 - cp + bp; M[45 + 6] = bp; M[45 + 7] = yp - bp;
      M[54 + 3] = cp - dp; M[54 + 4] = 1 - ep + dp; M[54 + 6] = dp; M[54 + 7] = ap - dp;
      M[63 + 4] = 1 - cp + bp; M[63 + 5] = yp - bp; M[63 + 7] = xv - bp; M[63 + 8] = bp;
      M[72 + 4] = 1 - ep + dp; M[72 + 5] = ap - dp; M[72 + 7] = cp - dp; M[72 + 8] = dp;
    } else {  // nb2 == ns2
      M[0] = cp; M[3] = 1 - cp;
      M[9 + 0] = bp; M[9 + 1] = xv - bp; M[9 + 3] = yp - bp; M[9 + 4] = 1 - cp + bp;
      M[18 + 1] = 1 - cp; M[18 + 2] = cp;
      M[27 + 3] = xv - bp; M[27 + 4] = 1 - cp + bp; M[27 + 6] = bp; M[27 + 7] = yp - bp;
      M[45 + 1] = yp - bp; M[45 + 2] = bp; M[45 + 4] = 1 - cp + bp; M[45 + 5] = xv - bp;
      M[54 + 6] = cp; M[54 + 7] = 1 - cp;
      M[63 + 4] = 1 - cp + bp; M[63 + 5] = yp - bp; M[63 + 7] = xv - bp; M[63 + 8] = bp;
      M[72 + 5] = 1 - cp; M[72 + 8] = cp;
    }
  }
}

// ---------------------------------------------------------------------------
// Kernel 1 (rot fused in): Wt[b][i][o][c] bf16 = sum_n,j rot[b,n,i,j]*w[n,o,c,j]
// Grid: (256 o, 4 bgroup), 128 threads; each thread owns 2 adjacent c ->
// packed 4B stores. Lanes 0..15 compute this bgroup's 16 rot matrices -> LDS.
// ---------------------------------------------------------------------------
__global__ __launch_bounds__(128) void wt_kernel(const float* __restrict__ weight,
                                                 const float* __restrict__ thetas,
                                                 const float* __restrict__ scales,
                                                 const float* __restrict__ lambdas,
                                                 ushort_t* __restrict__ wtout) {
  __shared__ float rotl[16][81];
  const int o = blockIdx.x, bg = blockIdx.y;
  const int tloc = threadIdx.x;  // 0..127
  const int c = tloc * 2;
  // issue weight loads first so they overlap the rot computation
  float wv0[4][9], wv1[4][9];
#pragma unroll
  for (int n = 0; n < 4; ++n) {
    const float* wp = weight + (((size_t)(n * 256 + o)) * 256 + c) * 9;
#pragma unroll
    for (int j = 0; j < 9; ++j) { wv0[n][j] = wp[j]; wv1[n][j] = wp[9 + j]; }
  }
  if (tloc < 16) {
    int gid = bg * 16 + tloc;  // == (b*4 + n) for b = bg*4 + tloc/4, n = tloc%4
    float M[81];
    rot_compute(thetas[gid], scales[gid], M);
    float lam = lambdas[gid];
#pragma unroll
    for (int i = 0; i < 81; ++i) rotl[tloc][i] = M[i] * lam;
  }
  __syncthreads();
#pragma unroll
  for (int bl = 0; bl < 4; ++bl) {
    const int b = bg * 4 + bl;
#pragma unroll
    for (int i = 0; i < 9; ++i) {
      float a0 = 0.0f, a1 = 0.0f;
#pragma unroll
      for (int n = 0; n < 4; ++n) {
        const float* r = &rotl[bl * 4 + n][i * 9];
#pragma unroll
        for (int j = 0; j < 9; ++j) {
          a0 = fmaf(r[j], wv0[n][j], a0);
          a1 = fmaf(r[j], wv1[n][j], a1);
        }
      }
      unsigned int word = (unsigned int)f2bf(a0) | ((unsigned int)f2bf(a1) << 16);
      *(unsigned int*)&wtout[((size_t)((b * 9 + i) * 256 + o)) * 256 + c] = word;
    }
  }
}

// ---------------------------------------------------------------------------
// Kernel 2: x [b][c][h][w] fp32 -> xpad [b][h+1][w+1][c] bf16, border zeroing
// fused. float4 global loads (16B/lane).
// ---------------------------------------------------------------------------
__global__ __launch_bounds__(256) void transpose_kernel(const float* __restrict__ x,
                                                        ushort_t* __restrict__ xpad) {
  __shared__ ushort_t tile[64][68];
  const int b = blockIdx.z, ct = blockIdx.y, st = blockIdx.x;  // st = h row
  const int t = threadIdx.x;
  const int c0 = ct * 64;
  const float* xb = x + ((size_t)(b * 256 + c0)) * 4096 + st * 64;
#pragma unroll
  for (int k = 0; k < 4; ++k) {
    int idx = t + 256 * k;            // 0..1023 over (c_l 0..63) x (w4 0,4,..60)
    int c_l = idx >> 4, w4 = (idx & 15) * 4;
    float4 v = *(const float4*)&xb[(size_t)c_l * 4096 + w4];
    tile[w4 + 0][c_l] = f2bf(v.x);
    tile[w4 + 1][c_l] = f2bf(v.y);
    tile[w4 + 2][c_l] = f2bf(v.z);
    tile[w4 + 3][c_l] = f2bf(v.w);
  }
  __syncthreads();
  const int c4 = (t & 15) * 4, wl = t >> 4;
  const size_t rowbase = (size_t)(b * 4356 + (st + 1) * 66) * 256 + c0;
#pragma unroll
  for (int k = 0; k < 4; ++k) {
    int w = wl + 16 * k;
    uint2 v = *(const uint2*)&tile[w][c4];
    *(uint2*)&xpad[rowbase + (size_t)(w + 1) * 256 + c4] = v;
  }
  // fused border zeroing
  if (t < 32) {
    int w = (t & 16) ? 65 : 0;
    int cc = (t & 15) * 4;
    *(uint2*)&xpad[rowbase + (size_t)w * 256 + cc] = make_uint2(0u, 0u);
  }
  if (st == 0 || st == 63) {
    const int h = (st == 0) ? 0 : 65;
    const size_t hb = (size_t)(b * 4356 + h * 66) * 256 + c0;
    for (int idx = t; idx < 66 * 16; idx += 256) {
      int w = idx >> 4, cc = (idx & 15) * 4;
      *(uint2*)&xpad[hb + (size_t)w * 256 + cc] = make_uint2(0u, 0u);
    }
  }
}

// ---------------------------------------------------------------------------
// Kernel 3: implicit-GEMM conv, bf16 MFMA.
// Tile 256 o x 128 hw, BK=32, 72 K-steps. NEW: 256 threads (4 waves), each
// wave owns 128x64 (8x4 MFMA frags) -> 12 LDS frag-reads per 32 MFMA
// (6 B/MFMA vs 8 before): per-CU LDS read traffic 128KB -> 96KB per K-step,
// rebalancing the LDS pipe (was 1540 cyc vs 1034 MFMA) which MfmaUtil=39%
// showed as the limiter. Sync structure unchanged: 3-stage LDS ring, raw
// s_barrier + counted vmcnt (now 6: each thread stages 6 chunks/step, two
// stages in flight = 12 outstanding, drain to 6). setprio REVERTED (R1: -3us,
// m190-consistent: no role-split in a lockstep-barrier schedule).
// ---------------------------------------------------------------------------
__device__ inline void gload16(const ushort_t* g, ushort_t* l) {
  __builtin_amdgcn_global_load_lds(
      (const __attribute__((address_space(1))) unsigned int*)g,
      (__attribute__((address_space(3))) unsigned int*)l, 16, 0, 0);
}

#define WAITB(N)                                                      \
  asm volatile("s_waitcnt vmcnt(" #N ") lgkmcnt(0)\n\ts_barrier" ::: "memory")

__global__ __launch_bounds__(256, 2) void conv_kernel(
    const ushort_t* __restrict__ xpad, const ushort_t* __restrict__ wt,
    float* __restrict__ out) {
  // six statically distinct LDS objects (3-stage ring)
  __shared__ __align__(16) ushort_t As0[8192], As1[8192], As2[8192];  // 16 KB each
  __shared__ __align__(16) ushort_t Bs0[4096], Bs1[4096], Bs2[4096];  //  8 KB each

  const int id = blockIdx.x;
  const int xcd = id & 7;
  const int jj = id >> 3;               // 0..63 within XCD
  const int b = xcd * 2 + (jj >> 5);    // 2 batches per XCD
  const int ntile = jj & 31;

  const int t = threadIdx.x;            // 0..255
  const int wave = t >> 6, lane = t & 63;
  const int wm = wave & 1, wn = wave >> 1;   // wave tile: 128 o x 64 hw
  const int lr = lane & 15, lq = lane >> 4;
  const int h0 = ntile * 2;

  const ushort_t* wt_b = wt + (size_t)b * 589824;     // 9*256*256
  const ushort_t* xp_b = xpad + (size_t)b * 1115136;  // 4356*256

  const int lrow = t >> 2;                           // 0..63
  const int cg8 = (((t & 3) ^ ((t >> 3) & 3)) * 8);  // swizzled global 16B chunk
  const int rsw = (lr >> 1) & 3;
  const int aoff = (wm * 128 + lr) * 32 + ((lq ^ rsw) * 8);
  const int boff = (wn * 64 + lr) * 32 + ((lq ^ rsw) * 8);

  f32x4 acc[8][4];
#pragma unroll
  for (int i = 0; i < 8; ++i)
#pragma unroll
    for (int j2 = 0; j2 < 4; ++j2) acc[i][j2] = (f32x4)(0.0f);

  auto stage = [&](int ks, ushort_t* Ad, ushort_t* Bd) {
    const int tap = ks >> 3;
    const int c0k = (ks & 7) << 5;
    const int kh = tap / 3, kw = tap - kh * 3;
    // A: Wt[b][tap][o 0..255][c0k..+31]; rows lrow + {0,64,128,192}
    const ushort_t* ga = wt_b + ((size_t)(tap * 256 + lrow)) * 256 + c0k + cg8;
    gload16(ga, Ad + wave * 512);
    gload16(ga + 64 * 256, Ad + 2048 + wave * 512);
    gload16(ga + 128 * 256, Ad + 4096 + wave * 512);
    gload16(ga + 192 * 256, Ad + 6144 + wave * 512);
    // B: n = lrow (0..63) and lrow+64 -> spatial (h0 + n/64 + kh, n%64 + kw)
    const int sp = (h0 + kh) * 66 + kw + lrow;
    gload16(xp_b + (size_t)sp * 256 + c0k + cg8, Bd + wave * 512);
    gload16(xp_b + (size_t)(sp + 66) * 256 + c0k + cg8, Bd + 2048 + wave * 512);
  };

  auto compute = [&](const ushort_t* Ab, const ushort_t* Bb) {
    s16x8 bfr[4];
#pragma unroll
    for (int ni = 0; ni < 4; ++ni)
      bfr[ni] = *(const s16x8*)(Bb + boff + ni * 512);
#pragma unroll
    for (int mi = 0; mi < 8; ++mi) {
      s16x8 af = *(const s16x8*)(Ab + aoff + mi * 512);
#pragma unroll
      for (int ni = 0; ni < 4; ++ni)
        acc[mi][ni] = __builtin_amdgcn_mfma_f32_16x16x32_bf16(af, bfr[ni], acc[mi][ni], 0, 0, 0);
    }
  };

  stage(0, As0, Bs0);
  stage(1, As1, Bs1);

  // 23 unrolled triples: compute ks = 0..68, stage through ks = 70.
#pragma unroll 1
  for (int kk = 0; kk < 23; ++kk) {
    const int ks = kk * 3;
    WAITB(6);                      // stage(ks) resident; stage(ks+1) in flight
    stage(ks + 2, As2, Bs2);
    compute(As0, Bs0);
    WAITB(6);
    stage(ks + 3, As0, Bs0);
    compute(As1, Bs1);
    WAITB(6);
    stage(ks + 4, As1, Bs1);
    compute(As2, Bs2);
  }
  // tail: outstanding = stage69 (As0), stage70 (As1)
  WAITB(6);                        // stage69 resident
  stage(71, As2, Bs2);
  compute(As0, Bs0);               // ks = 69
  WAITB(6);                        // stage70 resident (71's 6 in flight)
  compute(As1, Bs1);               // ks = 70
  WAITB(0);                        // full drain
  compute(As2, Bs2);               // ks = 71

  // Epilogue. C/D layout (m89): col(n) = lane&15, row(m) = (lane>>4)*4 + reg
  float* ob = out + ((size_t)(b * 256 + wm * 128)) * 4096 + ntile * 128 + wn * 64 + lr;
#pragma unroll
  for (int mi = 0; mi < 8; ++mi)
#pragma unroll
    for (int r = 0; r < 4; ++r) {
      float* orow = ob + (size_t)(mi * 16 + lq * 4 + r) * 4096;
#pragma unroll
      for (int ni = 0; ni < 4; ++ni) orow[ni * 16] = acc[mi][ni][r];
    }
}

// ---------------------------------------------------------------------------
extern "C" void kernel_launch(void* const* d_in, const int* in_sizes, int n_in,
                              void* d_out, int out_size, void* d_ws, size_t ws_size,
                              hipStream_t stream) {
  const float* x = (const float*)d_in[0];       // [16,256,64,64]
  const float* thetas = (const float*)d_in[1];  // [16,4]
  const float* scales = (const float*)d_in[2];  // [16,4]
  const float* lambdas = (const float*)d_in[3]; // [16,4]
  const float* weight = (const float*)d_in[4];  // [4,256,256,3,3]
  float* out = (float*)d_out;                   // [16,256,64,64]

  // workspace layout:
  //   Wt   bf16 [16][9][256][256]   @ 0         (18874368 B)
  //   xpad bf16 [16][66][66][256]   @ 18874368  (35684352 B)
  ushort_t* wt_ws = (ushort_t*)d_ws;
  ushort_t* xpad_ws = (ushort_t*)((char*)d_ws + 18874368);

  wt_kernel<<<dim3(256, 4), 128, 0, stream>>>(weight, thetas, scales, lambdas, wt_ws);
  transpose_kernel<<<dim3(64, 4, 16), 256, 0, stream>>>(x, xpad_ws);
  conv_kernel<<<512, 256, 0, stream>>>(xpad_ws, wt_ws, out);
}

// Round 4
// 211.073 us; speedup vs baseline: 1.1141x; 1.0222x over previous
//
#include <hip/hip_runtime.h>
#include <cstdint>
#include <cstddef>

typedef unsigned short ushort_t;
typedef __attribute__((ext_vector_type(4))) float f32x4;
typedef __attribute__((ext_vector_type(8))) short s16x8;

#define PI_4F 0.78539816339744830962f

// round-to-nearest-even fp32 -> bf16
__device__ inline ushort_t f2bf(float f) {
  unsigned int u = __float_as_uint(f);
  u = u + 0x7fffu + ((u >> 16) & 1u);
  return (ushort_t)(u >> 16);
}

// ---------------------------------------------------------------------------
// rot matrix for one (b, n): fills M[81] (unscaled).
// ---------------------------------------------------------------------------
__device__ void rot_compute(float t, float s, float* M) {
  float xv = cosf(t) * s, yv = sinf(t) * s;
  bool pos = (t >= 0.0f), big = (s >= 1.0f), m1 = (fabsf(t) <= PI_4F);
#pragma unroll
  for (int i = 0; i < 81; ++i) M[i] = 0.0f;
  M[36 + 4] = 1.0f;
  if (pos) {
    float a = xv - yv, bb = xv * yv, c = xv + yv;
    if (m1 && big) {  // pb1
      M[0] = a; M[1] = 1 - a;
      M[9 + 1] = 1 - yv; M[9 + 2] = yv;
      M[18 + 2] = a; M[18 + 5] = 1 - a;
      M[27 + 0] = yv; M[27 + 3] = 1 - yv;
      M[45 + 5] = 1 - yv; M[45 + 8] = yv;
      M[54 + 3] = 1 - a; M[54 + 6] = a;
      M[63 + 6] = yv; M[63 + 7] = 1 - yv;
      M[72 + 7] = 1 - a; M[72 + 8] = a;
    } else if (m1) {  // ps1
      float d = a * c, e = a + c;
      M[0] = d; M[1] = a - d; M[3] = c - d; M[4] = 1 - e + d;
      M[9 + 1] = xv - bb; M[9 + 2] = bb; M[9 + 4] = 1 - c + bb; M[9 + 5] = yv - bb;
      M[18 + 1] = c - d; M[18 + 2] = d; M[18 + 4] = 1 - e + d; M[18 + 5] = a - d;
      M[27 + 0] = bb; M[27 + 1] = yv - bb; M[27 + 3] = xv - bb; M[27 + 4] = 1 - c + bb;
      M[45 + 4] = 1 - c + bb; M[45 + 5] = xv - bb; M[45 + 7] = yv - bb; M[45 + 8] = bb;
      M[54 + 3] = a - d; M[54 + 4] = 1 - e + d; M[54 + 6] = d; M[54 + 7] = c - d;
      M[63 + 3] = yv - bb; M[63 + 4] = 1 - c + bb; M[63 + 6] = bb; M[63 + 7] = xv - bb;
      M[72 + 4] = 1 - e + d; M[72 + 5] = c - d; M[72 + 7] = a - d; M[72 + 8] = d;
    } else {  // pb2 == ps2
      M[0] = a; M[1] = 1 - a;
      M[9 + 1] = xv - bb; M[9 + 2] = bb; M[9 + 4] = 1 - c + bb; M[9 + 5] = yv - bb;
      M[18 + 2] = a; M[18 + 5] = 1 - a;
      M[27 + 0] = bb; M[27 + 1] = yv - bb; M[27 + 3] = xv - bb; M[27 + 4] = 1 - c + bb;
      M[45 + 4] = 1 - c + bb; M[45 + 5] = xv - bb; M[45 + 7] = yv - bb; M[45 + 8] = bb;
      M[54 + 3] = 1 - a; M[54 + 6] = a;
      M[63 + 3] = yv - bb; M[63 + 4] = 1 - c + bb; M[63 + 6] = bb; M[63 + 7] = xv - bb;
      M[72 + 7] = 1 - a; M[72 + 8] = a;
    }
  } else {
    float yp = -yv;
    float ap = xv - yp, bp = xv * yp, cp = xv + yp;
    if (m1 && big) {  // nb1
      M[0] = cp; M[3] = 1 - cp;
      M[9 + 0] = yp; M[9 + 1] = 1 - yp;
      M[18 + 1] = 1 - cp; M[18 + 2] = cp;
      M[27 + 3] = 1 - yp; M[27 + 6] = yp;
      M[45 + 2] = yp; M[45 + 5] = 1 - yp;
      M[54 + 6] = cp; M[54 + 7] = 1 - cp;
      M[63 + 7] = 1 - yp; M[63 + 8] = yp;
      M[72 + 5] = 1 - cp; M[72 + 8] = cp;
    } else if (m1) {  // ns1
      float dp = ap * cp, ep = ap + cp;
      M[0] = dp; M[1] = cp - dp; M[3] = ap - dp; M[4] = 1 - ep + dp;
      M[9 + 0] = bp; M[9 + 1] = xv - bp; M[9 + 3] = yp - bp; M[9 + 4] = 1 - cp + bp;
      M[18 + 1] = ap - dp; M[18 + 2] = dp; M[18 + 4] = 1 - ep + dp; M[18 + 5] = cp - dp;
      M[27 + 1] = yp - bp; M[27 + 2] = bp; M[27 + 4] = 1 - cp + bp; M[27 + 5] = xv - bp;
      M[45 + 3] = xv - bp; M[45 + 4] = 1 - cp + bp; M[45 + 6] = bp; M[45 + 7] = yp - bp;
      M[54 + 3] = cp - dp; M[54 + 4] = 1 - ep + dp; M[54 + 6] = dp; M[54 + 7] = ap - dp;
      M[63 + 4] = 1 - cp + bp; M[63 + 5] = yp - bp; M[63 + 7] = xv - bp; M[63 + 8] = bp;
      M[72 + 4] = 1 - ep + dp; M[72 + 5] = ap - dp; M[72 + 7] = cp - dp; M[72 + 8] = dp;
    } else {  // nb2 == ns2
      M[0] = cp; M[3] = 1 - cp;
      M[9 + 0] = bp; M[9 + 1] = xv - bp; M[9 + 3] = yp - bp; M[9 + 4] = 1 - cp + bp;
      M[18 + 1] = 1 - cp; M[18 + 2] = cp;
      M[27 + 3] = xv - bp; M[27 + 4] = 1 - cp + bp; M[27 + 6] = bp; M[27 + 7] = yp - bp;
      M[45 + 1] = yp - bp; M[45 + 2] = bp; M[45 + 4] = 1 - cp + bp; M[45 + 5] = xv - bp;
      M[54 + 6] = cp; M[54 + 7] = 1 - cp;
      M[63 + 4] = 1 - cp + bp; M[63 + 5] = yp - bp; M[63 + 7] = xv - bp; M[63 + 8] = bp;
      M[72 + 5] = 1 - cp; M[72 + 8] = cp;
    }
  }
}

// ---------------------------------------------------------------------------
// Fused prep kernel: blocks 0..511 = wt (weight transform), 512..4607 =
// transpose+pad. One dispatch instead of two.
//   wt: Wt[b][i][o][c] bf16 = sum_n,j rot[b,n,i,j]*w[n,o,c,j]; 256 thr = 2 o.
//   transpose: x [b][c][h][w] fp32 -> xpad [b][h+1][w+1][c] bf16 + borders.
// ---------------------------------------------------------------------------
__global__ __launch_bounds__(256) void prep_kernel(
    const float* __restrict__ x, const float* __restrict__ weight,
    const float* __restrict__ thetas, const float* __restrict__ scales,
    const float* __restrict__ lambdas, ushort_t* __restrict__ xpad,
    ushort_t* __restrict__ wtout) {
  __shared__ __align__(16) char smem[64 * 68 * 2];  // max(tile, rotl)
  const int bi = blockIdx.x;
  const int t = threadIdx.x;

  if (bi < 512) {
    // ---- weight-transform part: block handles (bg, o2*2 + half) ----
    float* rotl = (float*)smem;  // [16][81]
    const int bg = bi >> 7, o2 = bi & 127;
    const int half = t >> 7, tloc = t & 127;
    const int o = o2 * 2 + half;
    const int c = tloc * 2;
    float wv0[4][9], wv1[4][9];
#pragma unroll
    for (int n = 0; n < 4; ++n) {
      const float* wp = weight + (((size_t)(n * 256 + o)) * 256 + c) * 9;
#pragma unroll
      for (int j = 0; j < 9; ++j) { wv0[n][j] = wp[j]; wv1[n][j] = wp[9 + j]; }
    }
    if (t < 16) {
      int gid = bg * 16 + t;
      float M[81];
      rot_compute(thetas[gid], scales[gid], M);
      float lam = lambdas[gid];
#pragma unroll
      for (int i = 0; i < 81; ++i) rotl[t * 81 + i] = M[i] * lam;
    }
    __syncthreads();
#pragma unroll
    for (int bl = 0; bl < 4; ++bl) {
      const int b = bg * 4 + bl;
#pragma unroll
      for (int i = 0; i < 9; ++i) {
        float a0 = 0.0f, a1 = 0.0f;
#pragma unroll
        for (int n = 0; n < 4; ++n) {
          const float* r = &rotl[(bl * 4 + n) * 81 + i * 9];
#pragma unroll
          for (int j = 0; j < 9; ++j) {
            a0 = fmaf(r[j], wv0[n][j], a0);
            a1 = fmaf(r[j], wv1[n][j], a1);
          }
        }
        unsigned int word = (unsigned int)f2bf(a0) | ((unsigned int)f2bf(a1) << 16);
        *(unsigned int*)&wtout[((size_t)((b * 9 + i) * 256 + o)) * 256 + c] = word;
      }
    }
  } else {
    // ---- transpose part ----
    ushort_t (*tile)[68] = (ushort_t(*)[68])smem;
    const int bi2 = bi - 512;
    const int b = bi2 >> 8, ct = (bi2 >> 6) & 3, st = bi2 & 63;
    const int c0 = ct * 64;
    const float* xb = x + ((size_t)(b * 256 + c0)) * 4096 + st * 64;
#pragma unroll
    for (int k = 0; k < 4; ++k) {
      int idx = t + 256 * k;            // (c_l 0..63) x (w4 0,4,..60)
      int c_l = idx >> 4, w4 = (idx & 15) * 4;
      float4 v = *(const float4*)&xb[(size_t)c_l * 4096 + w4];
      tile[w4 + 0][c_l] = f2bf(v.x);
      tile[w4 + 1][c_l] = f2bf(v.y);
      tile[w4 + 2][c_l] = f2bf(v.z);
      tile[w4 + 3][c_l] = f2bf(v.w);
    }
    __syncthreads();
    const int c4 = (t & 15) * 4, wl = t >> 4;
    const size_t rowbase = (size_t)(b * 4356 + (st + 1) * 66) * 256 + c0;
#pragma unroll
    for (int k = 0; k < 4; ++k) {
      int w = wl + 16 * k;
      uint2 v = *(const uint2*)&tile[w][c4];
      *(uint2*)&xpad[rowbase + (size_t)(w + 1) * 256 + c4] = v;
    }
    // fused border zeroing
    if (t < 32) {
      int w = (t & 16) ? 65 : 0;
      int cc = (t & 15) * 4;
      *(uint2*)&xpad[rowbase + (size_t)w * 256 + cc] = make_uint2(0u, 0u);
    }
    if (st == 0 || st == 63) {
      const int h = (st == 0) ? 0 : 65;
      const size_t hb = (size_t)(b * 4356 + h * 66) * 256 + c0;
      for (int idx = t; idx < 66 * 16; idx += 256) {
        int w = idx >> 4, cc = (idx & 15) * 4;
        *(uint2*)&xpad[hb + (size_t)w * 256 + cc] = make_uint2(0u, 0u);
      }
    }
  }
}

// ---------------------------------------------------------------------------
// Kernel 3: implicit-GEMM conv, bf16 MFMA.
// Tile 256 o x 128 hw, BK=32, 72 K-steps, 256 threads (4 waves, 128x64/wave).
// Register-fragment pipelining: stage(ks+1) is complete+published at step ks;
// MFMAs of step ks read only REGISTERS (fragments prefetched during step
// ks-1), and step ks prefetches step ks+1's fragments during its MFMAs. The
// post-barrier lgkm stall (~150-250 cyc that phase-locked all waves; R0==R2
// wall at 2x occupancy proved barrier lock) leaves the critical path.
// Ring-3 safety: buf[ks%3] is dead at step start (frags in regs; all waves'
// fragloads drained by WAITB's lgkmcnt(0) BEFORE its barrier), so stage(ks+3)
// may overwrite it right after the barrier.
// ---------------------------------------------------------------------------
__device__ inline void gload16(const ushort_t* g, ushort_t* l) {
  __builtin_amdgcn_global_load_lds(
      (const __attribute__((address_space(1))) unsigned int*)g,
      (__attribute__((address_space(3))) unsigned int*)l, 16, 0, 0);
}

#define WAITB(N)                                                      \
  asm volatile("s_waitcnt vmcnt(" #N ") lgkmcnt(0)\n\ts_barrier" ::: "memory")

__global__ __launch_bounds__(256, 2) void conv_kernel(
    const ushort_t* __restrict__ xpad, const ushort_t* __restrict__ wt,
    float* __restrict__ out) {
  // six statically distinct LDS objects (3-stage ring)
  __shared__ __align__(16) ushort_t As0[8192], As1[8192], As2[8192];  // 16 KB each
  __shared__ __align__(16) ushort_t Bs0[4096], Bs1[4096], Bs2[4096];  //  8 KB each

  const int id = blockIdx.x;
  const int xcd = id & 7;
  const int jj = id >> 3;               // 0..63 within XCD
  const int b = xcd * 2 + (jj >> 5);    // 2 batches per XCD
  const int ntile = jj & 31;

  const int t = threadIdx.x;            // 0..255
  const int wave = t >> 6, lane = t & 63;
  const int wm = wave & 1, wn = wave >> 1;   // wave tile: 128 o x 64 hw
  const int lr = lane & 15, lq = lane >> 4;
  const int h0 = ntile * 2;

  const ushort_t* wt_b = wt + (size_t)b * 589824;     // 9*256*256
  const ushort_t* xp_b = xpad + (size_t)b * 1115136;  // 4356*256

  const int lrow = t >> 2;                           // 0..63
  const int cg8 = (((t & 3) ^ ((t >> 3) & 3)) * 8);  // swizzled global 16B chunk
  const int rsw = (lr >> 1) & 3;
  const int aoff = (wm * 128 + lr) * 32 + ((lq ^ rsw) * 8);
  const int boff = (wn * 64 + lr) * 32 + ((lq ^ rsw) * 8);

  f32x4 acc[8][4];
#pragma unroll
  for (int i = 0; i < 8; ++i)
#pragma unroll
    for (int j2 = 0; j2 < 4; ++j2) acc[i][j2] = (f32x4)(0.0f);

  s16x8 af0[8], bf0[4], af1[8], bf1[4];  // double-buffered fragment sets

  auto stage = [&](int ks, ushort_t* Ad, ushort_t* Bd) {
    const int tap = ks >> 3;
    const int c0k = (ks & 7) << 5;
    const int kh = tap / 3, kw = tap - kh * 3;
    const ushort_t* ga = wt_b + ((size_t)(tap * 256 + lrow)) * 256 + c0k + cg8;
    gload16(ga, Ad + wave * 512);
    gload16(ga + 64 * 256, Ad + 2048 + wave * 512);
    gload16(ga + 128 * 256, Ad + 4096 + wave * 512);
    gload16(ga + 192 * 256, Ad + 6144 + wave * 512);
    const int sp = (h0 + kh) * 66 + kw + lrow;
    gload16(xp_b + (size_t)sp * 256 + c0k + cg8, Bd + wave * 512);
    gload16(xp_b + (size_t)(sp + 66) * 256 + c0k + cg8, Bd + 2048 + wave * 512);
  };

  auto fragload = [&](const ushort_t* Ab, const ushort_t* Bb, s16x8* af, s16x8* bf) {
#pragma unroll
    for (int ni = 0; ni < 4; ++ni) bf[ni] = *(const s16x8*)(Bb + boff + ni * 512);
#pragma unroll
    for (int mi = 0; mi < 8; ++mi) af[mi] = *(const s16x8*)(Ab + aoff + mi * 512);
  };

  auto mfma_step = [&](const s16x8* af, const s16x8* bf) {
#pragma unroll
    for (int mi = 0; mi < 8; ++mi)
#pragma unroll
      for (int ni = 0; ni < 4; ++ni)
        acc[mi][ni] = __builtin_amdgcn_mfma_f32_16x16x32_bf16(af[mi], bf[ni], acc[mi][ni], 0, 0, 0);
  };

// step ks: WAITB completes stage(ks+1); stage(ks+3)->buf[ks%3] (dead buffer);
// fragload(ks+1) from buf[(ks+1)%3]; MFMA from current reg set.
#define STEP(KSS, SS, NS, AFC, BFC, AFN, BFN)                 \
  WAITB(6);                                                   \
  {                                                           \
    const int kss_ = (KSS) > 71 ? 71 : (KSS);                 \
    stage(kss_, As##SS, Bs##SS);                              \
  }                                                           \
  fragload(As##NS, Bs##NS, AFN, BFN);                         \
  mfma_step(AFC, BFC);

  // prologue: 3 stages in flight; wait 0,1 resident; preload frags(0)
  stage(0, As0, Bs0);
  stage(1, As1, Bs1);
  stage(2, As2, Bs2);
  asm volatile("s_waitcnt vmcnt(6) lgkmcnt(0)\n\ts_barrier" ::: "memory");
  fragload(As0, Bs0, af0, bf0);

  // 12 iterations x 6 steps (ring-3 x frag-parity-2); stage arg = ks+3.
#pragma unroll 1
  for (int kk = 0; kk < 12; ++kk) {
    const int ks0 = kk * 6;
    STEP(ks0 + 3, 0, 1, af0, bf0, af1, bf1);   // step ks0+0
    STEP(ks0 + 4, 1, 2, af1, bf1, af0, bf0);   // step ks0+1
    STEP(ks0 + 5, 2, 0, af0, bf0, af1, bf1);   // step ks0+2
    STEP(ks0 + 6, 0, 1, af1, bf1, af0, bf0);   // step ks0+3
    STEP(ks0 + 7, 1, 2, af0, bf0, af1, bf1);   // step ks0+4
    STEP(ks0 + 8, 2, 0, af1, bf1, af0, bf0);   // step ks0+5
  }
#undef STEP

  // Epilogue. C/D layout (m89): col(n) = lane&15, row(m) = (lane>>4)*4 + reg
  float* ob = out + ((size_t)(b * 256 + wm * 128)) * 4096 + ntile * 128 + wn * 64 + lr;
#pragma unroll
  for (int mi = 0; mi < 8; ++mi)
#pragma unroll
    for (int r = 0; r < 4; ++r) {
      float* orow = ob + (size_t)(mi * 16 + lq * 4 + r) * 4096;
#pragma unroll
      for (int ni = 0; ni < 4; ++ni) orow[ni * 16] = acc[mi][ni][r];
    }
}

// ---------------------------------------------------------------------------
extern "C" void kernel_launch(void* const* d_in, const int* in_sizes, int n_in,
                              void* d_out, int out_size, void* d_ws, size_t ws_size,
                              hipStream_t stream) {
  const float* x = (const float*)d_in[0];       // [16,256,64,64]
  const float* thetas = (const float*)d_in[1];  // [16,4]
  const float* scales = (const float*)d_in[2];  // [16,4]
  const float* lambdas = (const float*)d_in[3]; // [16,4]
  const float* weight = (const float*)d_in[4];  // [4,256,256,3,3]
  float* out = (float*)d_out;                   // [16,256,64,64]

  // workspace layout:
  //   Wt   bf16 [16][9][256][256]   @ 0         (18874368 B)
  //   xpad bf16 [16][66][66][256]   @ 18874368  (35684352 B)
  ushort_t* wt_ws = (ushort_t*)d_ws;
  ushort_t* xpad_ws = (ushort_t*)((char*)d_ws + 18874368);

  prep_kernel<<<4608, 256, 0, stream>>>(x, weight, thetas, scales, lambdas,
                                        xpad_ws, wt_ws);
  conv_kernel<<<512, 256, 0, stream>>>(xpad_ws, wt_ws, out);
}